// Round 4
// baseline (244.282 us; speedup 1.0000x reference)
//
#include <hip/hip_runtime.h>

// LinearKoopmanLayer: out[b,2f,t]   = c*x[b,2f,t] - s*x[b,2f+1,t]
//                     out[b,2f+1,t] = s*x[b,2f,t] + c*x[b,2f+1,t]
// a = amp[f]^dt[b], c = a*cos(freq[f]*dt[b]), s = a*sin(freq[f]*dt[b]).
//
// R4: concurrency-level experiment. R0-R3 falsified MLP (8-deep preload,
// R1), block churn (persistent 2048-block loop, R3), and store flavor
// (nt vs plain, R0/R2): all land at ~81 us / 2.4 TB/s with every CU pipe
// idle. The one invariant: 53-62% occupancy with thousands of concurrent
// 8-64 KiB streams. The in-capture control: rocclr fill sustains
// 6.7 TB/s at 9.5% occupancy (few, long streams). This version adopts
// the fill's regime: 256 blocks (exactly 1 per CU, 12.5% occupancy,
// zero tail), each streaming one contiguous 512 KiB region over 64
// iterations. A 4-deep static-indexed prefetch pipeline keeps 8 x 16B
// loads (8 KiB/wave, 32 KiB/CU) in flight - above the ~15 KiB
// latency-bandwidth product, so low wave count does not starve MLP.
// Coefficients per iteration via native transcendentals (v_sin/v_cos
// take revolutions -> 1/2pi scale); stores nt (never re-read), loads
// plain (input half-hits L3: FETCH 65.5 MB of 134 MB input).

constexpr int Bn = 256;
constexpr int Fn = 64;
constexpr int Tn = 1024;
constexpr int BLOCKS = 256;                   // 1 block per CU
constexpr int ITERS  = Bn * Fn / BLOCKS;      // 64 bf row-pairs per block
constexpr int DEPTH  = 4;                     // prefetch pipeline depth

typedef float v4f __attribute__((ext_vector_type(4)));

__global__ __launch_bounds__(256) void koopman_kernel(
    const float* __restrict__ x,
    const float* __restrict__ delta_t,
    const float* __restrict__ amplitudes,
    const float* __restrict__ frequencies,
    float* __restrict__ out) {
    const int t      = threadIdx.x;           // 0..255 covers one row (Tn/4 v4f)
    const int bfBase = blockIdx.x * ITERS;

    // Each bf pair is a contiguous 2048-float (512 v4f) region:
    //   [0,256) v4f = row 2f (x0), [256,512) v4f = row 2f+1 (x1).
    const v4f* __restrict__ xp = reinterpret_cast<const v4f*>(x)
                               + (size_t)bfBase * 512;
    v4f*       __restrict__ op = reinterpret_cast<v4f*>(out)
                               + (size_t)bfBase * 512;

    // Prologue: fill the 4-deep pipeline (8 loads in flight per thread).
    v4f p0[DEPTH], p1[DEPTH];
#pragma unroll
    for (int j = 0; j < DEPTH; ++j) {
        p0[j] = xp[j * 512 + t];
        p1[j] = xp[j * 512 + 256 + t];
    }

    // Main loop: unroll by DEPTH so slot index (j & 3) is compile-time
    // everywhere (rule #20: no runtime-indexed register arrays).
#pragma unroll 4
    for (int j = 0; j < ITERS; ++j) {
        const int sl = j & (DEPTH - 1);
        const v4f d0 = p0[sl];
        const v4f d1 = p1[sl];

        // Refill this slot for iteration j+DEPTH (uniform branch).
        if (j + DEPTH < ITERS) {
            p0[sl] = xp[(j + DEPTH) * 512 + t];
            p1[sl] = xp[(j + DEPTH) * 512 + 256 + t];
        }

        // Wave-uniform coefficients via native transcendentals.
        const int bf = bfBase + j;
        const int b  = bf >> 6;               // F = 64
        const int f  = bf & 63;
        const float d = delta_t[b];
        const float a = __builtin_amdgcn_exp2f(d * __builtin_amdgcn_logf(amplitudes[f]));
        const float rev = (frequencies[f] * d) * 0.15915494309189535f;
        const float s = a * __builtin_amdgcn_sinf(rev);
        const float c = a * __builtin_amdgcn_cosf(rev);

        const v4f r0 = c * d0 - s * d1;
        const v4f r1 = s * d0 + c * d1;
        __builtin_nontemporal_store(r0, &op[j * 512 + t]);
        __builtin_nontemporal_store(r1, &op[j * 512 + 256 + t]);
    }
}

extern "C" void kernel_launch(void* const* d_in, const int* in_sizes, int n_in,
                              void* d_out, int out_size, void* d_ws, size_t ws_size,
                              hipStream_t stream) {
    const float* x    = (const float*)d_in[0];
    const float* dt   = (const float*)d_in[1];
    const float* amp  = (const float*)d_in[2];
    const float* freq = (const float*)d_in[3];
    float* out = (float*)d_out;

    static_assert((Bn * Fn) % BLOCKS == 0, "grid divisibility");
    koopman_kernel<<<dim3(BLOCKS), dim3(256), 0, stream>>>(x, dt, amp, freq, out);
}

// Round 5
// 222.198 us; speedup vs baseline: 1.0994x; 1.0994x over previous
//
#include <hip/hip_runtime.h>

// LinearKoopmanLayer: out[b,2f,t]   = c*x[b,2f,t] - s*x[b,2f+1,t]
//                     out[b,2f+1,t] = s*x[b,2f,t] + c*x[b,2f+1,t]
// a = amp[f]^dt[b], c = a*cos(freq[f]*dt[b]), s = a*sin(freq[f]*dt[b]).
//
// FINAL (R5): byte-for-byte revert to the R1 kernel — the best
// harness-verified variant (223.25 us total). Session findings:
//  * Profiled kernel dispatch is ~80 us at 2.4 TB/s HBM with EVERY CU
//    pipe idle (VALUBusy <6%, MfmaUtil 0, no bank conflicts).
//  * Four orthogonal structural levers each measured NEUTRAL on the
//    dispatch: per-wave MLP depth (2->8 loads in flight, R1), nt vs
//    plain accesses (R0/R2), block churn (persistent 2048-block loop,
//    R3), concurrency level (16384 blocks @62% occ -> 256 blocks @10%
//    occ, R4). The ~2.4 TB/s mixed read+write rate under this harness's
//    memory state (poison-fill L3 residue; FETCH shows half the input
//    L3-resident) is not movable from inside the kernel.
//  * The timed graph total DID respond to one thing: cache pollution.
//    Removing nontemporal hints (R2) cost +8.4 us total with identical
//    kernel dispatch time — plain accesses evict the poison-fill's L3
//    lines and slow the neighboring fill dispatches. Deeper pipelines /
//    persistent blocks (R3/R4) worsened totals further (239, 244 us).
//    Hence: nontemporal on ALL x/out traffic, one-shot blocks.
//
// Structure: one 256-thread block per 4 consecutive (b,f) row-pairs;
// all 8x16B nt loads issued before any dependent math; block-uniform
// coefficients via raw AMDGCN transcendentals (v_log/v_exp/v_sin/v_cos;
// sin/cos take REVOLUTIONS, hence the 1/2pi scale) whose latency hides
// under the vmcnt wait; nt stores.

constexpr int Bn = 256;
constexpr int Fn = 64;
constexpr int Tn = 1024;
constexpr int CHUNKS = 4;              // (b,f) row-pairs per block

typedef float v4f __attribute__((ext_vector_type(4)));

__global__ __launch_bounds__(256) void koopman_kernel(
    const float* __restrict__ x,
    const float* __restrict__ delta_t,
    const float* __restrict__ amplitudes,
    const float* __restrict__ frequencies,
    float* __restrict__ out) {
    const int t   = threadIdx.x;               // 0..255, covers Tn/4 v4f
    const int bf0 = blockIdx.x * CHUNKS;       // first (b,f) pair

    // Each chunk is a contiguous 2048-float (512 v4f) region:
    //   [0,256) v4f = row 2f (x0), [256,512) v4f = row 2f+1 (x1).
    const v4f* __restrict__ xp = reinterpret_cast<const v4f*>(x)
                               + (size_t)bf0 * (2 * Tn / 4);
    v4f*       __restrict__ op = reinterpret_cast<v4f*>(out)
                               + (size_t)bf0 * (2 * Tn / 4);

    // 1) Issue ALL streaming loads first: 8 x 16B in flight per thread.
    v4f v0[CHUNKS], v1[CHUNKS];
#pragma unroll
    for (int j = 0; j < CHUNKS; ++j) {
        v0[j] = __builtin_nontemporal_load(&xp[j * 512 + t]);
        v1[j] = __builtin_nontemporal_load(&xp[j * 512 + 256 + t]);
    }

    // 2) Wave-uniform coefficient math (scalar loads + ~8 VALU / chunk),
    //    overlapped with the outstanding vmcnt by the scheduler.
    float cc[CHUNKS], ss[CHUNKS];
#pragma unroll
    for (int j = 0; j < CHUNKS; ++j) {
        const int bf = bf0 + j;
        const int b  = bf >> 6;                // F = 64
        const int f  = bf & 63;
        const float d = delta_t[b];
        // amp^d = exp2(d * log2(amp)), amp in [0.7,1.3]
        const float a = __builtin_amdgcn_exp2f(d * __builtin_amdgcn_logf(amplitudes[f]));
        // v_sin/v_cos take revolutions: sin(ang) = v_sin(ang / 2pi)
        const float rev = (frequencies[f] * d) * 0.15915494309189535f;
        ss[j] = a * __builtin_amdgcn_sinf(rev);
        cc[j] = a * __builtin_amdgcn_cosf(rev);
    }

    // 3) Rotate + store per chunk; chunk j only needs loads 2j,2j+1 so the
    //    compiler can retire stores under partial vmcnt waits.
#pragma unroll
    for (int j = 0; j < CHUNKS; ++j) {
        const v4f r0 = cc[j] * v0[j] - ss[j] * v1[j];
        const v4f r1 = ss[j] * v0[j] + cc[j] * v1[j];
        __builtin_nontemporal_store(r0, &op[j * 512 + t]);
        __builtin_nontemporal_store(r1, &op[j * 512 + 256 + t]);
    }
}

extern "C" void kernel_launch(void* const* d_in, const int* in_sizes, int n_in,
                              void* d_out, int out_size, void* d_ws, size_t ws_size,
                              hipStream_t stream) {
    const float* x    = (const float*)d_in[0];
    const float* dt   = (const float*)d_in[1];
    const float* amp  = (const float*)d_in[2];
    const float* freq = (const float*)d_in[3];
    float* out = (float*)d_out;

    static_assert((Bn * Fn) % CHUNKS == 0, "grid divisibility");
    koopman_kernel<<<dim3(Bn * Fn / CHUNKS), dim3(256), 0, stream>>>(x, dt, amp, freq, out);
}